// Round 8
// baseline (230.110 us; speedup 1.0000x reference)
//
#include <hip/hip_runtime.h>

#define USER_COUNT 100000
#define ITEM_COUNT 50000
#define N_NODES    150000   // USER_COUNT + ITEM_COUNT
#define EMB        64
#define N_EDGES    1250000
#define BATCH      4096

#define NBKT      147                 // ceil(150000 / 1024), bucket = row >> 10
#define BROWS     1024                // rows per bucket
#define A1_TILE   2048
#define A1_BLOCKS ((N_EDGES + A1_TILE - 1) / A1_TILE)   // 611
#define COLMASK   0x3FFFFu
#define ROW_ALLOC 150536              // >= NBKT*BROWS (150528), 16B padded
#define NLIST_PAD 150016
#define BITWORDS  4704                // ceil(150000/32)=4688, padded

#define CONCAT_BLOCKS 9375            // N_NODES*EMB/4 / 256
#define BHIST_BLOCKS  1221            // ceil(N_EDGES / 1024)

// bf16x2 pack/unpack (round-to-nearest-even; inputs are finite)
static __device__ __forceinline__ unsigned pack_bf16x2(float a, float b) {
    unsigned ua = __float_as_uint(a);
    unsigned ub = __float_as_uint(b);
    ua += 0x7FFFu + ((ua >> 16) & 1u);
    ub += 0x7FFFu + ((ub >> 16) & 1u);
    return (ua >> 16) | (ub & 0xFFFF0000u);
}
static __device__ __forceinline__ float2 unpack_bf16x2(unsigned v) {
    float2 r;
    r.x = __uint_as_float(v << 16);
    r.y = __uint_as_float(v & 0xFFFF0000u);
    return r;
}

// ---------------------------------------------------------------------------
// 32-lane-group SpMM row body (round-6 proven): lane owns dims (2l, 2l+1),
// unroll-4 => 4 independent row gathers in flight per group.
// ---------------------------------------------------------------------------
static __device__ __forceinline__ float2 spmm_row(const uint2* __restrict__ edges,
                                                  int s, int e,
                                                  const unsigned* __restrict__ xin,
                                                  int l) {
    float ax0 = 0.f, ay0 = 0.f, ax1 = 0.f, ay1 = 0.f;
    float ax2 = 0.f, ay2 = 0.f, ax3 = 0.f, ay3 = 0.f;
    int i = s;
    for (; i + 3 < e; i += 4) {
        uint2 e0 = edges[i];
        uint2 e1 = edges[i + 1];
        uint2 e2 = edges[i + 2];
        uint2 e3 = edges[i + 3];
        float w0 = __uint_as_float(e0.y);
        float w1 = __uint_as_float(e1.y);
        float w2 = __uint_as_float(e2.y);
        float w3 = __uint_as_float(e3.y);
        float2 v0 = unpack_bf16x2(xin[(size_t)(e0.x & COLMASK) * 32 + l]);
        float2 v1 = unpack_bf16x2(xin[(size_t)(e1.x & COLMASK) * 32 + l]);
        float2 v2 = unpack_bf16x2(xin[(size_t)(e2.x & COLMASK) * 32 + l]);
        float2 v3 = unpack_bf16x2(xin[(size_t)(e3.x & COLMASK) * 32 + l]);
        ax0 += w0 * v0.x; ay0 += w0 * v0.y;
        ax1 += w1 * v1.x; ay1 += w1 * v1.y;
        ax2 += w2 * v2.x; ay2 += w2 * v2.y;
        ax3 += w3 * v3.x; ay3 += w3 * v3.y;
    }
    for (; i < e; ++i) {
        uint2 e0 = edges[i];
        float w0 = __uint_as_float(e0.y);
        float2 v0 = unpack_bf16x2(xin[(size_t)(e0.x & COLMASK) * 32 + l]);
        ax0 += w0 * v0.x; ay0 += w0 * v0.y;
    }
    return make_float2((ax0 + ax1) + (ax2 + ax3), (ay0 + ay1) + (ay2 + ay3));
}

// ---------------------------------------------------------------------------
// Fused prep: blocks [0, CONCAT_BLOCKS) do ego->bf16 concat;
// blocks [CONCAT_BLOCKS, +BHIST_BLOCKS) do the bucket histogram.
// ---------------------------------------------------------------------------
__global__ void k_prep(const float* __restrict__ ue, const float* __restrict__ ie,
                       unsigned* __restrict__ x,
                       const int* __restrict__ row, int* __restrict__ gcount) {
    __shared__ int h[NBKT];
    int tid = threadIdx.x;
    if (blockIdx.x < CONCAT_BLOCKS) {
        const size_t nu4 = (size_t)USER_COUNT * EMB / 4;
        size_t i = (size_t)blockIdx.x * 256 + tid;
        float4 v = (i < nu4) ? ((const float4*)ue)[i] : ((const float4*)ie)[i - nu4];
        uint2 p;
        p.x = pack_bf16x2(v.x, v.y);
        p.y = pack_bf16x2(v.z, v.w);
        ((uint2*)x)[i] = p;
    } else {
        int bb = blockIdx.x - CONCAT_BLOCKS;
        if (tid < NBKT) h[tid] = 0;
        __syncthreads();
        int base = bb * 1024;
        #pragma unroll
        for (int j = 0; j < 4; ++j) {
            int e = base + j * 256 + tid;
            if (e < N_EDGES) atomicAdd(&h[row[e] >> 10], 1);
        }
        __syncthreads();
        if (tid < NBKT && h[tid]) atomicAdd(&gcount[tid], h[tid]);
    }
}

// ---------------------------------------------------------------------------
// Scan of 147 bucket counts -> gstart (exclusive) + gcursor; zero ncount.
// Only tid<=NBKT writes (round-4 bugfix).
// ---------------------------------------------------------------------------
__global__ void k_bscan(const int* __restrict__ gcount,
                        int* __restrict__ gstart, int* __restrict__ gcursor,
                        int* __restrict__ ncount) {
    __shared__ int sA[256], sB[256];
    int tid = threadIdx.x;
    int v = (tid < NBKT) ? gcount[tid] : 0;
    sA[tid] = v;
    __syncthreads();
    int* in = sA; int* out = sB;
    for (int off = 1; off < 256; off <<= 1) {
        out[tid] = in[tid] + ((tid >= off) ? in[tid - off] : 0);
        __syncthreads();
        int* t = in; in = out; out = t;
    }
    int excl = in[tid] - v;       // tid == NBKT: == N_EDGES (sentinel)
    if (tid <= NBKT) {
        gstart[tid]  = excl;
        gcursor[tid] = excl;
    }
    if (tid == 255) ncount[0] = 0;
}

// ---------------------------------------------------------------------------
// Pass A1: bucket-sort edges into edges_a with coherent (staged) writes.
// Record: {col | (row&1023)<<18, w_f32}
// ---------------------------------------------------------------------------
__global__ void k_binfill(const int* __restrict__ row, const int* __restrict__ col,
                          const float* __restrict__ w,
                          int* __restrict__ gcursor, uint2* __restrict__ edges_a) {
    __shared__ int cnt[256], cnt2[NBKT], gpos[NBKT], sc[NBKT];
    __shared__ int sA[256], sB[256];
    __shared__ uint2 srec[A1_TILE];
    __shared__ int  sdst[A1_TILE];
    int tid = threadIdx.x;
    cnt[tid] = 0;
    if (tid < NBKT) cnt2[tid] = 0;
    __syncthreads();

    int ebase   = blockIdx.x * A1_TILE;
    int tilecnt = min(A1_TILE, N_EDGES - ebase);

    int r[8], c[8]; float wv[8];
    #pragma unroll
    for (int j = 0; j < 8; ++j) {
        int e = ebase + j * 256 + tid;
        if (e < N_EDGES) {
            r[j] = row[e]; c[j] = col[e]; wv[j] = w[e];
            atomicAdd(&cnt[r[j] >> 10], 1);
        } else {
            r[j] = -1;
        }
    }
    __syncthreads();

    int* in = sA; int* out = sB;
    in[tid] = cnt[tid];
    __syncthreads();
    for (int off = 1; off < 256; off <<= 1) {
        out[tid] = in[tid] + ((tid >= off) ? in[tid - off] : 0);
        __syncthreads();
        int* t = in; in = out; out = t;
    }
    if (tid < NBKT) {
        sc[tid]   = in[tid] - cnt[tid];
        gpos[tid] = atomicAdd(&gcursor[tid], cnt[tid]);
    }
    __syncthreads();

    #pragma unroll
    for (int j = 0; j < 8; ++j) {
        if (r[j] >= 0) {
            int b  = r[j] >> 10;
            int lp = sc[b] + atomicAdd(&cnt2[b], 1);
            srec[lp] = make_uint2((unsigned)c[j] | ((unsigned)(r[j] & 1023) << 18),
                                  __float_as_uint(wv[j]));
            sdst[lp] = gpos[b] + (lp - sc[b]);
        }
    }
    __syncthreads();

    #pragma unroll
    for (int j = 0; j < 8; ++j) {
        int i = j * 256 + tid;
        if (i < tilecnt) edges_a[sdst[i]] = srec[i];
    }
}

// ---------------------------------------------------------------------------
// Pass A2, quarter-split: one block per (bucket, quarter) = 588 blocks.
// Each block scans its bucket's edges, keeps its 256-row quarter, computes
// the quarter base from per-quarter totals, writes row_start + edges_b.
// ---------------------------------------------------------------------------
__global__ __launch_bounds__(256) void k_csrfill(const int* __restrict__ gstart,
                                                 const uint2* __restrict__ edges_a,
                                                 uint2* __restrict__ edges_b,
                                                 int* __restrict__ row_start) {
    __shared__ int hist[256], cur[256], qtot[4];
    __shared__ int sA[256], sB[256];
    int tid   = threadIdx.x;
    int b     = blockIdx.x >> 2;
    int q     = blockIdx.x & 3;
    int base  = gstart[b];
    int count = gstart[b + 1] - base;

    hist[tid] = 0;
    if (tid < 4) qtot[tid] = 0;
    __syncthreads();

    int c0 = 0, c1 = 0, c2 = 0, c3 = 0;
    for (int i = tid; i < count; i += 256) {
        unsigned a = edges_a[base + i].x;
        int rl = (a >> 18) & 1023;
        int qq = rl >> 8;
        c0 += (qq == 0); c1 += (qq == 1); c2 += (qq == 2); c3 += (qq == 3);
        if (qq == q) atomicAdd(&hist[rl & 255], 1);
    }
    if (c0) atomicAdd(&qtot[0], c0);
    if (c1) atomicAdd(&qtot[1], c1);
    if (c2) atomicAdd(&qtot[2], c2);
    if (c3) atomicAdd(&qtot[3], c3);
    __syncthreads();

    int qbase = base;
    for (int k = 0; k < 4; ++k) if (k < q) qbase += qtot[k];

    // exclusive scan of hist[256]
    int hv = hist[tid];
    int* in = sA; int* out = sB;
    in[tid] = hv;
    __syncthreads();
    for (int off = 1; off < 256; off <<= 1) {
        out[tid] = in[tid] + ((tid >= off) ? in[tid - off] : 0);
        __syncthreads();
        int* t = in; in = out; out = t;
    }
    int excl = in[tid] - hv;
    row_start[b * BROWS + q * 256 + tid] = qbase + excl;
    cur[tid] = qbase + excl;
    __syncthreads();

    for (int i = tid; i < count; i += 256) {
        uint2 rec = edges_a[base + i];
        int rl = (rec.x >> 18) & 1023;
        if ((rl >> 8) != q) continue;
        int pos = atomicAdd(&cur[rl & 255], 1);
        edges_b[pos] = rec;
    }
}

// ---------------------------------------------------------------------------
// Mark+append (dedup'd): bit-array atomicOr; first setter appends to nlist.
// Covers selected nodes + cols of their edges (rows whose x2 is needed).
// ---------------------------------------------------------------------------
static __device__ __forceinline__ void bit_append(int n, unsigned* __restrict__ bits,
                                                  int* __restrict__ list,
                                                  int* __restrict__ count) {
    unsigned bit = 1u << (n & 31);
    unsigned old = atomicOr(&bits[n >> 5], bit);
    if (!(old & bit)) {
        int pos = atomicAdd(count, 1);
        list[pos] = n;
    }
}

__global__ void k_mark(const int* __restrict__ users, const int* __restrict__ items,
                       const int* __restrict__ row_start,
                       const uint2* __restrict__ edges_b,
                       unsigned* __restrict__ bits,
                       int* __restrict__ nlist, int* __restrict__ ncount) {
    int t = blockIdx.x * blockDim.x + threadIdx.x;
    int g = t >> 3;
    int l = t & 7;
    if (g >= 2 * BATCH) return;
    int node = (g < BATCH) ? users[g] : USER_COUNT + items[g - BATCH];
    if (l == 0) bit_append(node, bits, nlist, ncount);
    int s = row_start[node], e = row_start[node + 1];
    for (int i = s + l; i < e; i += 8)
        bit_append((int)(edges_b[i].x & COLMASK), bits, nlist, ncount);
}

// ---------------------------------------------------------------------------
// Full gather SpMM: 32-lane group per node
// ---------------------------------------------------------------------------
__global__ void k_spmm_bf16(const int* __restrict__ row_start,
                            const uint2* __restrict__ edges,
                            const unsigned* __restrict__ xin,
                            unsigned* __restrict__ xout) {
    int g = blockIdx.x * 8 + (threadIdx.x >> 5);
    int l = threadIdx.x & 31;
    if (g >= N_NODES) return;
    float2 a = spmm_row(edges, row_start[g], row_start[g + 1], xin, l);
    xout[(size_t)g * 32 + l] = pack_bf16x2(a.x, a.y);
}

// ---------------------------------------------------------------------------
// List-driven gather SpMM (layer 2 prune): only listed (unique) rows
// ---------------------------------------------------------------------------
__global__ void k_spmm_list(const int* __restrict__ row_start,
                            const uint2* __restrict__ edges,
                            const unsigned* __restrict__ xin,
                            unsigned* __restrict__ xout,
                            const int* __restrict__ list,
                            const int* __restrict__ count) {
    int gi = blockIdx.x * 8 + (threadIdx.x >> 5);
    if (gi >= *count) return;
    int g = list[gi];
    int l = threadIdx.x & 31;
    float2 a = spmm_row(edges, row_start[g], row_start[g + 1], xin, l);
    xout[(size_t)g * 32 + l] = pack_bf16x2(a.x, a.y);
}

// ---------------------------------------------------------------------------
// Fused epilogue: out[g] = 0.25*(ego + x1 + x2 + layer3(x2)), full write.
// One 32-lane group per selected slot.
// ---------------------------------------------------------------------------
__global__ void k_epilogue(const int* __restrict__ users,
                           const int* __restrict__ items,
                           const float* __restrict__ ue,
                           const float* __restrict__ ie,
                           const unsigned* __restrict__ x1,
                           const unsigned* __restrict__ x2,
                           const int* __restrict__ row_start,
                           const uint2* __restrict__ edges,
                           float* __restrict__ out) {
    int g = blockIdx.x * 8 + (threadIdx.x >> 5);
    int l = threadIdx.x & 31;
    if (g >= 2 * BATCH) return;
    int node = (g < BATCH) ? users[g] : USER_COUNT + items[g - BATCH];
    float2 l3 = spmm_row(edges, row_start[node], row_start[node + 1], x2, l);
    const float* ego = (node < USER_COUNT)
                         ? ue + (size_t)node * EMB
                         : ie + (size_t)(node - USER_COUNT) * EMB;
    float2 e = ((const float2*)ego)[l];
    float2 a = unpack_bf16x2(x1[(size_t)node * 32 + l]);
    float2 b = unpack_bf16x2(x2[(size_t)node * 32 + l]);
    float2 r;
    r.x = 0.25f * (e.x + a.x + b.x + l3.x);
    r.y = 0.25f * (e.y + a.y + b.y + l3.y);
    ((float2*)out)[(size_t)g * 32 + l] = r;
}

extern "C" void kernel_launch(void* const* d_in, const int* in_sizes, int n_in,
                              void* d_out, int out_size, void* d_ws, size_t ws_size,
                              hipStream_t stream) {
    const float* user_emb    = (const float*)d_in[0];
    const float* item_emb    = (const float*)d_in[1];
    const int*   edge_row    = (const int*)d_in[2];
    const int*   edge_col    = (const int*)d_in[3];
    const float* edge_weight = (const float*)d_in[4];
    const int*   users       = (const int*)d_in[5];
    const int*   items       = (const int*)d_in[6];
    float* out = (float*)d_out;

    // ws layout
    const size_t node_u32 = (size_t)N_NODES * 32;     // 19.2 MB per table
    unsigned* xa        = (unsigned*)d_ws;            // ego (bf16)
    unsigned* xb        = xa + node_u32;              // x1
    unsigned* xc        = xb + node_u32;              // x2 (pruned rows only)
    int*      row_start = (int*)(xc + node_u32);      // ROW_ALLOC ints
    int*      gcount    = row_start + ROW_ALLOC;      // 256
    unsigned* bits      = (unsigned*)(gcount + 256);  // BITWORDS (zeroed w/ gcount)
    int*      gstart    = (int*)(bits + BITWORDS);    // 256
    int*      gcursor   = gstart + 256;               // 256
    int*      ncount    = gcursor + 256;              // 16
    int*      nlist     = ncount + 16;                // NLIST_PAD
    uint2*    edges_a   = (uint2*)(nlist + NLIST_PAD);   // 10 MB
    uint2*    edges_b   = edges_a + N_EDGES;             // 10 MB

    // single memset: gcount + dedup bit-array (contiguous)
    hipMemsetAsync(gcount, 0, (256 + BITWORDS) * sizeof(int), stream);

    // prep: concat->bf16 + bucket histogram (fused)
    k_prep<<<CONCAT_BLOCKS + BHIST_BLOCKS, 256, 0, stream>>>(user_emb, item_emb,
                                                             xa, edge_row, gcount);

    // CSR build
    k_bscan<<<1, 256, 0, stream>>>(gcount, gstart, gcursor, ncount);
    k_binfill<<<A1_BLOCKS, 256, 0, stream>>>(edge_row, edge_col, edge_weight,
                                             gcursor, edges_a);
    k_csrfill<<<NBKT * 4, 256, 0, stream>>>(gstart, edges_a, edges_b, row_start);

    // mark+append (dedup'd x2-needed rows)
    k_mark<<<(2 * BATCH * 8 + 255) / 256, 256, 0, stream>>>(users, items, row_start,
                                                            edges_b, bits,
                                                            nlist, ncount);

    // layers
    k_spmm_bf16<<<(N_NODES + 7) / 8, 256, 0, stream>>>(row_start, edges_b, xa, xb);
    k_spmm_list<<<(N_NODES + 7) / 8, 256, 0, stream>>>(row_start, edges_b, xb, xc,
                                                       nlist, ncount);

    // fused epilogue
    k_epilogue<<<(2 * BATCH + 7) / 8, 256, 0, stream>>>(users, items,
                                                        user_emb, item_emb,
                                                        xb, xc, row_start, edges_b,
                                                        out);
}

// Round 9
// 214.635 us; speedup vs baseline: 1.0721x; 1.0721x over previous
//
#include <hip/hip_runtime.h>

#define USER_COUNT 100000
#define ITEM_COUNT 50000
#define N_NODES    150000   // USER_COUNT + ITEM_COUNT
#define EMB        64
#define N_EDGES    1250000
#define BATCH      4096

#define NBKT      147                 // ceil(150000 / 1024), bucket = row >> 10
#define BROWS     1024                // rows per bucket
#define A1_TILE   2048
#define A1_BLOCKS ((N_EDGES + A1_TILE - 1) / A1_TILE)   // 611
#define PSTR      160                 // partT row stride (ints), >= NBKT
#define COLMASK   0x3FFFFu
#define ROW_ALLOC 150536              // >= NBKT*BROWS (150528), 16B padded
#define NLIST_PAD 150016
#define BITWORDS  4704                // ceil(150000/32)=4688, padded

// bf16x2 pack/unpack (round-to-nearest-even; inputs are finite)
static __device__ __forceinline__ unsigned pack_bf16x2(float a, float b) {
    unsigned ua = __float_as_uint(a);
    unsigned ub = __float_as_uint(b);
    ua += 0x7FFFu + ((ua >> 16) & 1u);
    ub += 0x7FFFu + ((ub >> 16) & 1u);
    return (ua >> 16) | (ub & 0xFFFF0000u);
}
static __device__ __forceinline__ float2 unpack_bf16x2(unsigned v) {
    float2 r;
    r.x = __uint_as_float(v << 16);
    r.y = __uint_as_float(v & 0xFFFF0000u);
    return r;
}

// ---------------------------------------------------------------------------
// 32-lane-group SpMM row body over a bf16 table (round-6 proven): lane owns
// dims (2l,2l+1); unroll-4 => 4 independent row gathers in flight per group.
// ---------------------------------------------------------------------------
static __device__ __forceinline__ float2 spmm_row(const uint2* __restrict__ edges,
                                                  int s, int e,
                                                  const unsigned* __restrict__ xin,
                                                  int l) {
    float ax0 = 0.f, ay0 = 0.f, ax1 = 0.f, ay1 = 0.f;
    float ax2 = 0.f, ay2 = 0.f, ax3 = 0.f, ay3 = 0.f;
    int i = s;
    for (; i + 3 < e; i += 4) {
        uint2 e0 = edges[i];
        uint2 e1 = edges[i + 1];
        uint2 e2 = edges[i + 2];
        uint2 e3 = edges[i + 3];
        float w0 = __uint_as_float(e0.y);
        float w1 = __uint_as_float(e1.y);
        float w2 = __uint_as_float(e2.y);
        float w3 = __uint_as_float(e3.y);
        float2 v0 = unpack_bf16x2(xin[(size_t)(e0.x & COLMASK) * 32 + l]);
        float2 v1 = unpack_bf16x2(xin[(size_t)(e1.x & COLMASK) * 32 + l]);
        float2 v2 = unpack_bf16x2(xin[(size_t)(e2.x & COLMASK) * 32 + l]);
        float2 v3 = unpack_bf16x2(xin[(size_t)(e3.x & COLMASK) * 32 + l]);
        ax0 += w0 * v0.x; ay0 += w0 * v0.y;
        ax1 += w1 * v1.x; ay1 += w1 * v1.y;
        ax2 += w2 * v2.x; ay2 += w2 * v2.y;
        ax3 += w3 * v3.x; ay3 += w3 * v3.y;
    }
    for (; i < e; ++i) {
        uint2 e0 = edges[i];
        float w0 = __uint_as_float(e0.y);
        float2 v0 = unpack_bf16x2(xin[(size_t)(e0.x & COLMASK) * 32 + l]);
        ax0 += w0 * v0.x; ay0 += w0 * v0.y;
    }
    return make_float2((ax0 + ax1) + (ax2 + ax3), (ay0 + ay1) + (ay2 + ay3));
}

// Same body but gathering from the f32 ego inputs (ue/ie) — no concat table.
static __device__ __forceinline__ const float* ego_ptr(unsigned c,
                                                       const float* __restrict__ ue,
                                                       const float* __restrict__ ie) {
    return (c < USER_COUNT) ? ue + (size_t)c * EMB
                            : ie + (size_t)(c - USER_COUNT) * EMB;
}

static __device__ __forceinline__ float2 spmm_row_f32(const uint2* __restrict__ edges,
                                                      int s, int e,
                                                      const float* __restrict__ ue,
                                                      const float* __restrict__ ie,
                                                      int l) {
    float ax0 = 0.f, ay0 = 0.f, ax1 = 0.f, ay1 = 0.f;
    float ax2 = 0.f, ay2 = 0.f, ax3 = 0.f, ay3 = 0.f;
    int i = s;
    for (; i + 3 < e; i += 4) {
        uint2 e0 = edges[i];
        uint2 e1 = edges[i + 1];
        uint2 e2 = edges[i + 2];
        uint2 e3 = edges[i + 3];
        float w0 = __uint_as_float(e0.y);
        float w1 = __uint_as_float(e1.y);
        float w2 = __uint_as_float(e2.y);
        float w3 = __uint_as_float(e3.y);
        float2 v0 = ((const float2*)ego_ptr(e0.x & COLMASK, ue, ie))[l];
        float2 v1 = ((const float2*)ego_ptr(e1.x & COLMASK, ue, ie))[l];
        float2 v2 = ((const float2*)ego_ptr(e2.x & COLMASK, ue, ie))[l];
        float2 v3 = ((const float2*)ego_ptr(e3.x & COLMASK, ue, ie))[l];
        ax0 += w0 * v0.x; ay0 += w0 * v0.y;
        ax1 += w1 * v1.x; ay1 += w1 * v1.y;
        ax2 += w2 * v2.x; ay2 += w2 * v2.y;
        ax3 += w3 * v3.x; ay3 += w3 * v3.y;
    }
    for (; i < e; ++i) {
        uint2 e0 = edges[i];
        float w0 = __uint_as_float(e0.y);
        float2 v0 = ((const float2*)ego_ptr(e0.x & COLMASK, ue, ie))[l];
        ax0 += w0 * v0.x; ay0 += w0 * v0.y;
    }
    return make_float2((ax0 + ax1) + (ax2 + ax3), (ay0 + ay1) + (ay2 + ay3));
}

// ---------------------------------------------------------------------------
// Per-block bucket histogram, NO global atomics: block bb (same 2048-edge
// tile as binfill) writes its 147 counts to partT[bb*PSTR + t] (block-private
// contiguous lines -> no cross-XCD false sharing).
// ---------------------------------------------------------------------------
__global__ void k_hist(const int* __restrict__ row, int* __restrict__ partT) {
    __shared__ int h[PSTR];
    int tid = threadIdx.x;
    if (tid < PSTR) h[tid] = 0;
    __syncthreads();
    int base = blockIdx.x * A1_TILE;
    #pragma unroll
    for (int j = 0; j < 8; ++j) {
        int e = base + j * 256 + tid;
        if (e < N_EDGES) atomicAdd(&h[row[e] >> 10], 1);
    }
    __syncthreads();
    if (tid < NBKT) partT[blockIdx.x * PSTR + tid] = h[tid];
}

// ---------------------------------------------------------------------------
// Single block: per-bucket totals -> gstart (exclusive scan, sentinel), then
// column-exclusive-scan partT in place so partT[bb][t] = global write base
// for block bb's bucket-t run in binfill. No atomics downstream.
// ---------------------------------------------------------------------------
__global__ void k_scanall(int* __restrict__ partT, int* __restrict__ gstart) {
    __shared__ int sA[256], sB[256];
    int tid = threadIdx.x;
    int tot = 0;
    if (tid < NBKT) {
        #pragma unroll 4
        for (int bb = 0; bb < A1_BLOCKS; ++bb)
            tot += partT[bb * PSTR + tid];
    }
    sA[tid] = tot;
    __syncthreads();
    int* in = sA; int* out = sB;
    for (int off = 1; off < 256; off <<= 1) {
        out[tid] = in[tid] + ((tid >= off) ? in[tid - off] : 0);
        __syncthreads();
        int* t = in; in = out; out = t;
    }
    int excl = in[tid] - tot;     // tid == NBKT: == N_EDGES (sentinel)
    if (tid <= NBKT) gstart[tid] = excl;
    if (tid < NBKT) {
        int run = excl;
        for (int bb = 0; bb < A1_BLOCKS; ++bb) {
            int idx = bb * PSTR + tid;
            int v = partT[idx];
            partT[idx] = run;
            run += v;
        }
    }
}

// ---------------------------------------------------------------------------
// Pass A1: bucket-sort edges into edges_a with coherent (staged) writes.
// Per-(block,bucket) base read from scanned partT — no global atomics.
// Record: {col | (row&1023)<<18, w_f32}
// ---------------------------------------------------------------------------
__global__ void k_binfill(const int* __restrict__ row, const int* __restrict__ col,
                          const float* __restrict__ w,
                          const int* __restrict__ partT,
                          uint2* __restrict__ edges_a) {
    __shared__ int cnt[256], cnt2[NBKT], gpos[NBKT], sc[NBKT];
    __shared__ int sA[256], sB[256];
    __shared__ uint2 srec[A1_TILE];
    __shared__ int  sdst[A1_TILE];
    int tid = threadIdx.x;
    cnt[tid] = 0;
    if (tid < NBKT) cnt2[tid] = 0;
    __syncthreads();

    int ebase   = blockIdx.x * A1_TILE;
    int tilecnt = min(A1_TILE, N_EDGES - ebase);

    int r[8], c[8]; float wv[8];
    #pragma unroll
    for (int j = 0; j < 8; ++j) {
        int e = ebase + j * 256 + tid;
        if (e < N_EDGES) {
            r[j] = row[e]; c[j] = col[e]; wv[j] = w[e];
            atomicAdd(&cnt[r[j] >> 10], 1);
        } else {
            r[j] = -1;
        }
    }
    __syncthreads();

    int* in = sA; int* out = sB;
    in[tid] = cnt[tid];
    __syncthreads();
    for (int off = 1; off < 256; off <<= 1) {
        out[tid] = in[tid] + ((tid >= off) ? in[tid - off] : 0);
        __syncthreads();
        int* t = in; in = out; out = t;
    }
    if (tid < NBKT) {
        sc[tid]   = in[tid] - cnt[tid];
        gpos[tid] = partT[blockIdx.x * PSTR + tid];   // scanned base, no atomic
    }
    __syncthreads();

    #pragma unroll
    for (int j = 0; j < 8; ++j) {
        if (r[j] >= 0) {
            int b  = r[j] >> 10;
            int lp = sc[b] + atomicAdd(&cnt2[b], 1);
            srec[lp] = make_uint2((unsigned)c[j] | ((unsigned)(r[j] & 1023) << 18),
                                  __float_as_uint(wv[j]));
            sdst[lp] = gpos[b] + (lp - sc[b]);
        }
    }
    __syncthreads();

    #pragma unroll
    for (int j = 0; j < 8; ++j) {
        int i = j * 256 + tid;
        if (i < tilecnt) edges_a[sdst[i]] = srec[i];
    }
}

// ---------------------------------------------------------------------------
// Pass A2: per-bucket exact CSR, one 1024-thread block per bucket.
// 2 passes over the bucket's edges; all writes block-local.
// ---------------------------------------------------------------------------
__global__ __launch_bounds__(1024) void k_csrfill(const int* __restrict__ gstart,
                                                  const uint2* __restrict__ edges_a,
                                                  uint2* __restrict__ edges_b,
                                                  int* __restrict__ row_start) {
    __shared__ int hist[BROWS], cur[BROWS];
    __shared__ int sA[BROWS], sB[BROWS];
    int tid   = threadIdx.x;
    int b     = blockIdx.x;
    int base  = gstart[b];
    int count = gstart[b + 1] - base;

    hist[tid] = 0;
    __syncthreads();
    for (int i = tid; i < count; i += 1024)
        atomicAdd(&hist[(edges_a[base + i].x >> 18) & 1023], 1);
    __syncthreads();

    int hv = hist[tid];
    int* in = sA; int* out = sB;
    in[tid] = hv;
    __syncthreads();
    for (int off = 1; off < 1024; off <<= 1) {
        out[tid] = in[tid] + ((tid >= off) ? in[tid - off] : 0);
        __syncthreads();
        int* t = in; in = out; out = t;
    }
    int excl = in[tid] - hv;
    row_start[b * BROWS + tid] = base + excl;
    cur[tid] = base + excl;
    __syncthreads();

    for (int i = tid; i < count; i += 1024) {
        uint2 rec = edges_a[base + i];
        int rl = (rec.x >> 18) & 1023;
        int pos = atomicAdd(&cur[rl], 1);
        edges_b[pos] = rec;
    }
}

// ---------------------------------------------------------------------------
// Mark+append (dedup'd): bit-array atomicOr; first setter appends to nlist.
// Covers selected nodes + cols of their edges (rows whose x2 is needed).
// ---------------------------------------------------------------------------
static __device__ __forceinline__ void bit_append(int n, unsigned* __restrict__ bits,
                                                  int* __restrict__ list,
                                                  int* __restrict__ count) {
    unsigned bit = 1u << (n & 31);
    unsigned old = atomicOr(&bits[n >> 5], bit);
    if (!(old & bit)) {
        int pos = atomicAdd(count, 1);
        list[pos] = n;
    }
}

__global__ void k_mark(const int* __restrict__ users, const int* __restrict__ items,
                       const int* __restrict__ row_start,
                       const uint2* __restrict__ edges_b,
                       unsigned* __restrict__ bits,
                       int* __restrict__ nlist, int* __restrict__ ncount) {
    int t = blockIdx.x * blockDim.x + threadIdx.x;
    int g = t >> 3;
    int l = t & 7;
    if (g >= 2 * BATCH) return;
    int node = (g < BATCH) ? users[g] : USER_COUNT + items[g - BATCH];
    if (l == 0) bit_append(node, bits, nlist, ncount);
    int s = row_start[node], e = row_start[node + 1];
    for (int i = s + l; i < e; i += 8)
        bit_append((int)(edges_b[i].x & COLMASK), bits, nlist, ncount);
}

// ---------------------------------------------------------------------------
// Layer-1 SpMM: gathers directly from f32 ue/ie (no concat table), bf16 out.
// ---------------------------------------------------------------------------
__global__ void k_spmm_l1(const int* __restrict__ row_start,
                          const uint2* __restrict__ edges,
                          const float* __restrict__ ue,
                          const float* __restrict__ ie,
                          unsigned* __restrict__ xout) {
    int g = blockIdx.x * 8 + (threadIdx.x >> 5);
    int l = threadIdx.x & 31;
    if (g >= N_NODES) return;
    float2 a = spmm_row_f32(edges, row_start[g], row_start[g + 1], ue, ie, l);
    xout[(size_t)g * 32 + l] = pack_bf16x2(a.x, a.y);
}

// ---------------------------------------------------------------------------
// List-driven gather SpMM (layer 2 prune): only listed (unique) rows
// ---------------------------------------------------------------------------
__global__ void k_spmm_list(const int* __restrict__ row_start,
                            const uint2* __restrict__ edges,
                            const unsigned* __restrict__ xin,
                            unsigned* __restrict__ xout,
                            const int* __restrict__ list,
                            const int* __restrict__ count) {
    int gi = blockIdx.x * 8 + (threadIdx.x >> 5);
    if (gi >= *count) return;
    int g = list[gi];
    int l = threadIdx.x & 31;
    float2 a = spmm_row(edges, row_start[g], row_start[g + 1], xin, l);
    xout[(size_t)g * 32 + l] = pack_bf16x2(a.x, a.y);
}

// ---------------------------------------------------------------------------
// Fused epilogue: out[g] = 0.25*(ego + x1 + x2 + layer3(x2)), full write.
// ---------------------------------------------------------------------------
__global__ void k_epilogue(const int* __restrict__ users,
                           const int* __restrict__ items,
                           const float* __restrict__ ue,
                           const float* __restrict__ ie,
                           const unsigned* __restrict__ x1,
                           const unsigned* __restrict__ x2,
                           const int* __restrict__ row_start,
                           const uint2* __restrict__ edges,
                           float* __restrict__ out) {
    int g = blockIdx.x * 8 + (threadIdx.x >> 5);
    int l = threadIdx.x & 31;
    if (g >= 2 * BATCH) return;
    int node = (g < BATCH) ? users[g] : USER_COUNT + items[g - BATCH];
    float2 l3 = spmm_row(edges, row_start[node], row_start[node + 1], x2, l);
    float2 e = ((const float2*)ego_ptr((unsigned)node, ue, ie))[l];
    float2 a = unpack_bf16x2(x1[(size_t)node * 32 + l]);
    float2 b = unpack_bf16x2(x2[(size_t)node * 32 + l]);
    float2 r;
    r.x = 0.25f * (e.x + a.x + b.x + l3.x);
    r.y = 0.25f * (e.y + a.y + b.y + l3.y);
    ((float2*)out)[(size_t)g * 32 + l] = r;
}

extern "C" void kernel_launch(void* const* d_in, const int* in_sizes, int n_in,
                              void* d_out, int out_size, void* d_ws, size_t ws_size,
                              hipStream_t stream) {
    const float* user_emb    = (const float*)d_in[0];
    const float* item_emb    = (const float*)d_in[1];
    const int*   edge_row    = (const int*)d_in[2];
    const int*   edge_col    = (const int*)d_in[3];
    const float* edge_weight = (const float*)d_in[4];
    const int*   users       = (const int*)d_in[5];
    const int*   items       = (const int*)d_in[6];
    float* out = (float*)d_out;

    // ws layout (~60 MB)
    const size_t node_u32 = (size_t)N_NODES * 32;     // 19.2 MB per bf16 table
    unsigned* xb        = (unsigned*)d_ws;            // x1
    unsigned* xc        = xb + node_u32;              // x2 (pruned rows only)
    int*      row_start = (int*)(xc + node_u32);      // ROW_ALLOC ints
    int*      gstart    = row_start + ROW_ALLOC;      // 256
    int*      partT     = gstart + 256;               // A1_BLOCKS*PSTR = 97760
    unsigned* bits      = (unsigned*)(partT + A1_BLOCKS * PSTR);  // BITWORDS
    int*      ncount    = (int*)(bits + BITWORDS);    // 16
    int*      nlist     = ncount + 16;                // NLIST_PAD
    uint2*    edges_a   = (uint2*)(nlist + NLIST_PAD);   // 10 MB
    uint2*    edges_b   = edges_a + N_EDGES;             // 10 MB

    // single small memset: dedup bit-array + ncount (contiguous)
    hipMemsetAsync(bits, 0, (BITWORDS + 16) * sizeof(int), stream);

    // ---------- CSR build (atomic-free) ----------
    k_hist<<<A1_BLOCKS, 256, 0, stream>>>(edge_row, partT);
    k_scanall<<<1, 256, 0, stream>>>(partT, gstart);
    k_binfill<<<A1_BLOCKS, 256, 0, stream>>>(edge_row, edge_col, edge_weight,
                                             partT, edges_a);
    k_csrfill<<<NBKT, 1024, 0, stream>>>(gstart, edges_a, edges_b, row_start);

    // ---------- mark+append (dedup'd x2-needed rows) ----------
    k_mark<<<(2 * BATCH * 8 + 255) / 256, 256, 0, stream>>>(users, items, row_start,
                                                            edges_b, bits,
                                                            nlist, ncount);

    // ---------- layers ----------
    k_spmm_l1<<<(N_NODES + 7) / 8, 256, 0, stream>>>(row_start, edges_b,
                                                     user_emb, item_emb, xb);
    k_spmm_list<<<(N_NODES + 7) / 8, 256, 0, stream>>>(row_start, edges_b, xb, xc,
                                                       nlist, ncount);

    // ---------- fused epilogue ----------
    k_epilogue<<<(2 * BATCH + 7) / 8, 256, 0, stream>>>(users, items,
                                                        user_emb, item_emb,
                                                        xb, xc, row_start, edges_b,
                                                        out);
}

// Round 10
// 160.204 us; speedup vs baseline: 1.4364x; 1.3398x over previous
//
#include <hip/hip_runtime.h>

#define USER_COUNT 100000
#define ITEM_COUNT 50000
#define N_NODES    150000   // USER_COUNT + ITEM_COUNT
#define EMB        64
#define N_EDGES    1250000
#define BATCH      4096

#define NBKT      147                 // ceil(150000 / 1024), bucket = row >> 10
#define BROWS     1024                // rows per bucket
#define A1_TILE   2048
#define A1_BLOCKS ((N_EDGES + A1_TILE - 1) / A1_TILE)   // 611
#define PSTR      160                 // partT row stride (ints), >= NBKT
#define COLMASK   0x3FFFFu
#define ROW_ALLOC 150536              // >= NBKT*BROWS (150528), 16B padded
#define NLIST_PAD 150016
#define BITWORDS  4704                // ceil(150000/32)=4688, padded

#define CONCAT_BLOCKS 9375            // N_NODES*EMB/4 / 256
// k_prep grid = CONCAT_BLOCKS + A1_BLOCKS

// bf16x2 pack/unpack (round-to-nearest-even; inputs are finite)
static __device__ __forceinline__ unsigned pack_bf16x2(float a, float b) {
    unsigned ua = __float_as_uint(a);
    unsigned ub = __float_as_uint(b);
    ua += 0x7FFFu + ((ua >> 16) & 1u);
    ub += 0x7FFFu + ((ub >> 16) & 1u);
    return (ua >> 16) | (ub & 0xFFFF0000u);
}
static __device__ __forceinline__ float2 unpack_bf16x2(unsigned v) {
    float2 r;
    r.x = __uint_as_float(v << 16);
    r.y = __uint_as_float(v & 0xFFFF0000u);
    return r;
}

static __device__ __forceinline__ const float* ego_ptr(unsigned c,
                                                       const float* __restrict__ ue,
                                                       const float* __restrict__ ie) {
    return (c < USER_COUNT) ? ue + (size_t)c * EMB
                            : ie + (size_t)(c - USER_COUNT) * EMB;
}

// ---------------------------------------------------------------------------
// 32-lane-group SpMM row body over a bf16 table (round-6 proven, 45 µs):
// lane owns dims (2l,2l+1); unroll-4 => 4 row gathers in flight per group.
// ---------------------------------------------------------------------------
static __device__ __forceinline__ float2 spmm_row(const uint2* __restrict__ edges,
                                                  int s, int e,
                                                  const unsigned* __restrict__ xin,
                                                  int l) {
    float ax0 = 0.f, ay0 = 0.f, ax1 = 0.f, ay1 = 0.f;
    float ax2 = 0.f, ay2 = 0.f, ax3 = 0.f, ay3 = 0.f;
    int i = s;
    for (; i + 3 < e; i += 4) {
        uint2 e0 = edges[i];
        uint2 e1 = edges[i + 1];
        uint2 e2 = edges[i + 2];
        uint2 e3 = edges[i + 3];
        float w0 = __uint_as_float(e0.y);
        float w1 = __uint_as_float(e1.y);
        float w2 = __uint_as_float(e2.y);
        float w3 = __uint_as_float(e3.y);
        float2 v0 = unpack_bf16x2(xin[(size_t)(e0.x & COLMASK) * 32 + l]);
        float2 v1 = unpack_bf16x2(xin[(size_t)(e1.x & COLMASK) * 32 + l]);
        float2 v2 = unpack_bf16x2(xin[(size_t)(e2.x & COLMASK) * 32 + l]);
        float2 v3 = unpack_bf16x2(xin[(size_t)(e3.x & COLMASK) * 32 + l]);
        ax0 += w0 * v0.x; ay0 += w0 * v0.y;
        ax1 += w1 * v1.x; ay1 += w1 * v1.y;
        ax2 += w2 * v2.x; ay2 += w2 * v2.y;
        ax3 += w3 * v3.x; ay3 += w3 * v3.y;
    }
    for (; i < e; ++i) {
        uint2 e0 = edges[i];
        float w0 = __uint_as_float(e0.y);
        float2 v0 = unpack_bf16x2(xin[(size_t)(e0.x & COLMASK) * 32 + l]);
        ax0 += w0 * v0.x; ay0 += w0 * v0.y;
    }
    return make_float2((ax0 + ax1) + (ax2 + ax3), (ay0 + ay1) + (ay2 + ay3));
}

// ---------------------------------------------------------------------------
// Fused prep: blocks [0, CONCAT_BLOCKS) do ego->bf16 concat; blocks
// [CONCAT_BLOCKS, +A1_BLOCKS) do the per-block bucket histogram (NO global
// atomics: block bb writes its 147 counts to partT[bb*PSTR+t], private lines).
// ---------------------------------------------------------------------------
__global__ void k_prep(const float* __restrict__ ue, const float* __restrict__ ie,
                       unsigned* __restrict__ x,
                       const int* __restrict__ row, int* __restrict__ partT) {
    __shared__ int h[PSTR];
    int tid = threadIdx.x;
    if (blockIdx.x < CONCAT_BLOCKS) {
        const size_t nu4 = (size_t)USER_COUNT * EMB / 4;
        size_t i = (size_t)blockIdx.x * 256 + tid;
        float4 v = (i < nu4) ? ((const float4*)ue)[i] : ((const float4*)ie)[i - nu4];
        uint2 p;
        p.x = pack_bf16x2(v.x, v.y);
        p.y = pack_bf16x2(v.z, v.w);
        ((uint2*)x)[i] = p;
    } else {
        int bb = blockIdx.x - CONCAT_BLOCKS;
        if (tid < PSTR) h[tid] = 0;
        __syncthreads();
        int base = bb * A1_TILE;
        #pragma unroll
        for (int j = 0; j < 8; ++j) {
            int e = base + j * 256 + tid;
            if (e < N_EDGES) atomicAdd(&h[row[e] >> 10], 1);
        }
        __syncthreads();
        if (tid < NBKT) partT[bb * PSTR + tid] = h[tid];
    }
}

// ---------------------------------------------------------------------------
// Parallel column scan: block t exclusive-scans partT[:,t] (611 entries)
// in place and writes the column total to gtot[t].
// ---------------------------------------------------------------------------
__global__ void k_scanbkt(int* __restrict__ partT, int* __restrict__ gtot) {
    __shared__ int sA[256], sB[256];
    int t   = blockIdx.x;
    int tid = threadIdx.x;
    int v0 = 0, v1 = 0, v2 = 0;
    int b0 = tid * 3;
    if (b0 + 0 < A1_BLOCKS) v0 = partT[(b0 + 0) * PSTR + t];
    if (b0 + 1 < A1_BLOCKS) v1 = partT[(b0 + 1) * PSTR + t];
    if (b0 + 2 < A1_BLOCKS) v2 = partT[(b0 + 2) * PSTR + t];
    int s = v0 + v1 + v2;
    sA[tid] = s;
    __syncthreads();
    int* in = sA; int* out = sB;
    for (int off = 1; off < 256; off <<= 1) {
        out[tid] = in[tid] + ((tid >= off) ? in[tid - off] : 0);
        __syncthreads();
        int* tmp = in; in = out; out = tmp;
    }
    int run = in[tid] - s;     // exclusive base for this thread's 3 entries
    if (b0 + 0 < A1_BLOCKS) { partT[(b0 + 0) * PSTR + t] = run; run += v0; }
    if (b0 + 1 < A1_BLOCKS) { partT[(b0 + 1) * PSTR + t] = run; run += v1; }
    if (b0 + 2 < A1_BLOCKS) { partT[(b0 + 2) * PSTR + t] = run; }
    if (tid == 255) gtot[t] = in[255];
}

// ---------------------------------------------------------------------------
// Tiny cross-bucket scan: gtot[147] -> gstart (exclusive + sentinel); zero
// ncount. Only tid<=NBKT writes.
// ---------------------------------------------------------------------------
__global__ void k_scan2(const int* __restrict__ gtot,
                        int* __restrict__ gstart, int* __restrict__ ncount) {
    __shared__ int sA[256], sB[256];
    int tid = threadIdx.x;
    int v = (tid < NBKT) ? gtot[tid] : 0;
    sA[tid] = v;
    __syncthreads();
    int* in = sA; int* out = sB;
    for (int off = 1; off < 256; off <<= 1) {
        out[tid] = in[tid] + ((tid >= off) ? in[tid - off] : 0);
        __syncthreads();
        int* t = in; in = out; out = t;
    }
    int excl = in[tid] - v;       // tid == NBKT: == N_EDGES (sentinel)
    if (tid <= NBKT) gstart[tid] = excl;
    if (tid == 255) ncount[0] = 0;
}

// ---------------------------------------------------------------------------
// Pass A1: bucket-sort edges into edges_a with coherent (staged) writes.
// Per-(block,bucket) base = gstart[t] + scanned partT[bb][t] — no atomics.
// Record: {col | (row&1023)<<18, w_f32}
// ---------------------------------------------------------------------------
__global__ void k_binfill(const int* __restrict__ row, const int* __restrict__ col,
                          const float* __restrict__ w,
                          const int* __restrict__ partT,
                          const int* __restrict__ gstart,
                          uint2* __restrict__ edges_a) {
    __shared__ int cnt[256], cnt2[NBKT], gpos[NBKT], sc[NBKT];
    __shared__ int sA[256], sB[256];
    __shared__ uint2 srec[A1_TILE];
    __shared__ int  sdst[A1_TILE];
    int tid = threadIdx.x;
    cnt[tid] = 0;
    if (tid < NBKT) cnt2[tid] = 0;
    __syncthreads();

    int ebase   = blockIdx.x * A1_TILE;
    int tilecnt = min(A1_TILE, N_EDGES - ebase);

    int r[8], c[8]; float wv[8];
    #pragma unroll
    for (int j = 0; j < 8; ++j) {
        int e = ebase + j * 256 + tid;
        if (e < N_EDGES) {
            r[j] = row[e]; c[j] = col[e]; wv[j] = w[e];
            atomicAdd(&cnt[r[j] >> 10], 1);
        } else {
            r[j] = -1;
        }
    }
    __syncthreads();

    int* in = sA; int* out = sB;
    in[tid] = cnt[tid];
    __syncthreads();
    for (int off = 1; off < 256; off <<= 1) {
        out[tid] = in[tid] + ((tid >= off) ? in[tid - off] : 0);
        __syncthreads();
        int* t = in; in = out; out = t;
    }
    if (tid < NBKT) {
        sc[tid]   = in[tid] - cnt[tid];
        gpos[tid] = gstart[tid] + partT[blockIdx.x * PSTR + tid];
    }
    __syncthreads();

    #pragma unroll
    for (int j = 0; j < 8; ++j) {
        if (r[j] >= 0) {
            int b  = r[j] >> 10;
            int lp = sc[b] + atomicAdd(&cnt2[b], 1);
            srec[lp] = make_uint2((unsigned)c[j] | ((unsigned)(r[j] & 1023) << 18),
                                  __float_as_uint(wv[j]));
            sdst[lp] = gpos[b] + (lp - sc[b]);
        }
    }
    __syncthreads();

    #pragma unroll
    for (int j = 0; j < 8; ++j) {
        int i = j * 256 + tid;
        if (i < tilecnt) edges_a[sdst[i]] = srec[i];
    }
}

// ---------------------------------------------------------------------------
// Pass A2: per-bucket exact CSR, one 1024-thread block per bucket.
// 2 passes over the bucket's edges; all writes block-local.
// ---------------------------------------------------------------------------
__global__ __launch_bounds__(1024) void k_csrfill(const int* __restrict__ gstart,
                                                  const uint2* __restrict__ edges_a,
                                                  uint2* __restrict__ edges_b,
                                                  int* __restrict__ row_start) {
    __shared__ int hist[BROWS], cur[BROWS];
    __shared__ int sA[BROWS], sB[BROWS];
    int tid   = threadIdx.x;
    int b     = blockIdx.x;
    int base  = gstart[b];
    int count = gstart[b + 1] - base;

    hist[tid] = 0;
    __syncthreads();
    for (int i = tid; i < count; i += 1024)
        atomicAdd(&hist[(edges_a[base + i].x >> 18) & 1023], 1);
    __syncthreads();

    int hv = hist[tid];
    int* in = sA; int* out = sB;
    in[tid] = hv;
    __syncthreads();
    for (int off = 1; off < 1024; off <<= 1) {
        out[tid] = in[tid] + ((tid >= off) ? in[tid - off] : 0);
        __syncthreads();
        int* t = in; in = out; out = t;
    }
    int excl = in[tid] - hv;
    row_start[b * BROWS + tid] = base + excl;
    cur[tid] = base + excl;
    __syncthreads();

    for (int i = tid; i < count; i += 1024) {
        uint2 rec = edges_a[base + i];
        int rl = (rec.x >> 18) & 1023;
        int pos = atomicAdd(&cur[rl], 1);
        edges_b[pos] = rec;
    }
}

// ---------------------------------------------------------------------------
// Mark+append (dedup'd): bit-array atomicOr; first setter appends to nlist.
// ---------------------------------------------------------------------------
static __device__ __forceinline__ void bit_append(int n, unsigned* __restrict__ bits,
                                                  int* __restrict__ list,
                                                  int* __restrict__ count) {
    unsigned bit = 1u << (n & 31);
    unsigned old = atomicOr(&bits[n >> 5], bit);
    if (!(old & bit)) {
        int pos = atomicAdd(count, 1);
        list[pos] = n;
    }
}

__global__ void k_mark(const int* __restrict__ users, const int* __restrict__ items,
                       const int* __restrict__ row_start,
                       const uint2* __restrict__ edges_b,
                       unsigned* __restrict__ bits,
                       int* __restrict__ nlist, int* __restrict__ ncount) {
    int t = blockIdx.x * blockDim.x + threadIdx.x;
    int g = t >> 3;
    int l = t & 7;
    if (g >= 2 * BATCH) return;
    int node = (g < BATCH) ? users[g] : USER_COUNT + items[g - BATCH];
    if (l == 0) bit_append(node, bits, nlist, ncount);
    int s = row_start[node], e = row_start[node + 1];
    for (int i = s + l; i < e; i += 8)
        bit_append((int)(edges_b[i].x & COLMASK), bits, nlist, ncount);
}

// ---------------------------------------------------------------------------
// Full gather SpMM over bf16 table: 32-lane group per node
// ---------------------------------------------------------------------------
__global__ void k_spmm_bf16(const int* __restrict__ row_start,
                            const uint2* __restrict__ edges,
                            const unsigned* __restrict__ xin,
                            unsigned* __restrict__ xout) {
    int g = blockIdx.x * 8 + (threadIdx.x >> 5);
    int l = threadIdx.x & 31;
    if (g >= N_NODES) return;
    float2 a = spmm_row(edges, row_start[g], row_start[g + 1], xin, l);
    xout[(size_t)g * 32 + l] = pack_bf16x2(a.x, a.y);
}

// ---------------------------------------------------------------------------
// List-driven gather SpMM (layer 2 prune): only listed (unique) rows
// ---------------------------------------------------------------------------
__global__ void k_spmm_list(const int* __restrict__ row_start,
                            const uint2* __restrict__ edges,
                            const unsigned* __restrict__ xin,
                            unsigned* __restrict__ xout,
                            const int* __restrict__ list,
                            const int* __restrict__ count) {
    int gi = blockIdx.x * 8 + (threadIdx.x >> 5);
    if (gi >= *count) return;
    int g = list[gi];
    int l = threadIdx.x & 31;
    float2 a = spmm_row(edges, row_start[g], row_start[g + 1], xin, l);
    xout[(size_t)g * 32 + l] = pack_bf16x2(a.x, a.y);
}

// ---------------------------------------------------------------------------
// Fused epilogue: out[g] = 0.25*(ego + x1 + x2 + layer3(x2)), full write.
// ---------------------------------------------------------------------------
__global__ void k_epilogue(const int* __restrict__ users,
                           const int* __restrict__ items,
                           const float* __restrict__ ue,
                           const float* __restrict__ ie,
                           const unsigned* __restrict__ x1,
                           const unsigned* __restrict__ x2,
                           const int* __restrict__ row_start,
                           const uint2* __restrict__ edges,
                           float* __restrict__ out) {
    int g = blockIdx.x * 8 + (threadIdx.x >> 5);
    int l = threadIdx.x & 31;
    if (g >= 2 * BATCH) return;
    int node = (g < BATCH) ? users[g] : USER_COUNT + items[g - BATCH];
    float2 l3 = spmm_row(edges, row_start[node], row_start[node + 1], x2, l);
    float2 e = ((const float2*)ego_ptr((unsigned)node, ue, ie))[l];
    float2 a = unpack_bf16x2(x1[(size_t)node * 32 + l]);
    float2 b = unpack_bf16x2(x2[(size_t)node * 32 + l]);
    float2 r;
    r.x = 0.25f * (e.x + a.x + b.x + l3.x);
    r.y = 0.25f * (e.y + a.y + b.y + l3.y);
    ((float2*)out)[(size_t)g * 32 + l] = r;
}

extern "C" void kernel_launch(void* const* d_in, const int* in_sizes, int n_in,
                              void* d_out, int out_size, void* d_ws, size_t ws_size,
                              hipStream_t stream) {
    const float* user_emb    = (const float*)d_in[0];
    const float* item_emb    = (const float*)d_in[1];
    const int*   edge_row    = (const int*)d_in[2];
    const int*   edge_col    = (const int*)d_in[3];
    const float* edge_weight = (const float*)d_in[4];
    const int*   users       = (const int*)d_in[5];
    const int*   items       = (const int*)d_in[6];
    float* out = (float*)d_out;

    // ws layout (~80 MB)
    const size_t node_u32 = (size_t)N_NODES * 32;     // 19.2 MB per bf16 table
    unsigned* xa        = (unsigned*)d_ws;            // ego (bf16)
    unsigned* xb        = xa + node_u32;              // x1
    unsigned* xc        = xb + node_u32;              // x2 (pruned rows only)
    int*      row_start = (int*)(xc + node_u32);      // ROW_ALLOC ints
    int*      gstart    = row_start + ROW_ALLOC;      // 256
    int*      gtot      = gstart + 256;               // 256
    int*      partT     = gtot + 256;                 // A1_BLOCKS*PSTR = 97760
    unsigned* bits      = (unsigned*)(partT + A1_BLOCKS * PSTR);  // BITWORDS
    int*      ncount    = (int*)(bits + BITWORDS);    // 16
    int*      nlist     = ncount + 16;                // NLIST_PAD
    uint2*    edges_a   = (uint2*)(nlist + NLIST_PAD);   // 10 MB
    uint2*    edges_b   = edges_a + N_EDGES;             // 10 MB

    // single small memset: dedup bit-array + ncount (contiguous)
    hipMemsetAsync(bits, 0, (BITWORDS + 16) * sizeof(int), stream);

    // ---------- prep: concat->bf16 + per-block histogram (fused, no atomics)
    k_prep<<<CONCAT_BLOCKS + A1_BLOCKS, 256, 0, stream>>>(user_emb, item_emb,
                                                          xa, edge_row, partT);

    // ---------- CSR build (atomic-free scans) ----------
    k_scanbkt<<<NBKT, 256, 0, stream>>>(partT, gtot);
    k_scan2<<<1, 256, 0, stream>>>(gtot, gstart, ncount);
    k_binfill<<<A1_BLOCKS, 256, 0, stream>>>(edge_row, edge_col, edge_weight,
                                             partT, gstart, edges_a);
    k_csrfill<<<NBKT, 1024, 0, stream>>>(gstart, edges_a, edges_b, row_start);

    // ---------- mark+append (dedup'd x2-needed rows) ----------
    k_mark<<<(2 * BATCH * 8 + 255) / 256, 256, 0, stream>>>(users, items, row_start,
                                                            edges_b, bits,
                                                            nlist, ncount);

    // ---------- layers ----------
    k_spmm_bf16<<<(N_NODES + 7) / 8, 256, 0, stream>>>(row_start, edges_b, xa, xb);
    k_spmm_list<<<(N_NODES + 7) / 8, 256, 0, stream>>>(row_start, edges_b, xb, xc,
                                                       nlist, ncount);

    // ---------- fused epilogue ----------
    k_epilogue<<<(2 * BATCH + 7) / 8, 256, 0, stream>>>(users, items,
                                                        user_emb, item_emb,
                                                        xb, xc, row_start, edges_b,
                                                        out);
}